// Round 6
// baseline (215.641 us; speedup 1.0000x reference)
//
#include <hip/hip_runtime.h>
#include <math.h>
#include <stdint.h>

#define HW    112
#define HW2   (112 * 112)
#define NIMG  64
#define CIN   128
#define TILEF (18 * HW)    // 2016 staged floats per buffer
#define TILEP 2032         // padded buffer stride (16B multiple)
#define NWF   (2 * CIN * 9)  // 2304 conv1 weights

__device__ __forceinline__ float gelu_exact(float v) {
    return 0.5f * v * (1.0f + erff(v * 0.70710678118654752f));
}

// ---------------------------------------------------------------------------
// K1: g[n][oc][h][w] = gelu(conv3x3(x, w1) + b1), all 128 ic in one block.
// 3-slot rotating LDS pipeline, counted vmcnt (never 0 in steady state),
// raw s_barrier (no vmcnt(0) drain). 256 thr; thread = 7 px row, both oc.
// Per-wave stage = exactly 2 global_load_lds insts (count4 >= 448 always),
// so vmcnt bookkeeping is exact: steady outstanding 6, wait vmcnt(4).
// ---------------------------------------------------------------------------
__global__ __launch_bounds__(256) void k1_conv_gelu(
    const float* __restrict__ x, const float* __restrict__ w1,
    const float* __restrict__ b1, float* __restrict__ g) {
    __shared__ __align__(16) float tile[3][TILEP];
    __shared__ float wlds[NWF];

    const int tid = threadIdx.x;
    const int bx  = blockIdx.x;   // 0..6 h-tiles
    const int n   = blockIdx.y;
    const int h0  = bx * 16;

    const int tx   = tid & 15;
    const int ty   = tid >> 4;
    const int col0 = tx * 7;

    // ---- one-time init: weights -> LDS, zero border rows in all 3 slots ----
    for (int j = tid; j < NWF; j += 256) wlds[j] = w1[j];
    if (bx == 0 && tid < HW) {
        tile[0][tid] = 0.f; tile[1][tid] = 0.f; tile[2][tid] = 0.f;
    }
    if (bx == 6 && tid < HW) {
        tile[0][17 * HW + tid] = 0.f; tile[1][17 * HW + tid] = 0.f; tile[2][17 * HW + tid] = 0.f;
    }

    const int    ldsoff = (bx == 0) ? HW : 0;                 // skip zero row 0
    const int    count4 = (bx == 0 || bx == 6) ? 476 : 504;   // float4s staged
    const size_t srcoff = (bx == 0) ? 0 : (size_t)(h0 - 1) * HW;
    const float* xn = x + (size_t)n * CIN * HW2 + srcoff;

    const float lmask = (col0 > 0) ? 1.f : 0.f;
    const float rmask = (col0 + 7 < HW) ? 1.f : 0.f;
    const int   loff  = (col0 > 0) ? -1 : 0;
    const int   roff  = (col0 + 7 < HW) ? 7 : 0;
    const float bb0 = b1[0], bb1 = b1[1];

    float acc0[7] = {0.f, 0.f, 0.f, 0.f, 0.f, 0.f, 0.f};
    float acc1[7] = {0.f, 0.f, 0.f, 0.f, 0.f, 0.f, 0.f};

#define STAGE(CH, SLOT)                                                        \
    do {                                                                       \
        const float* _src = xn + (size_t)(CH) * HW2;                           \
        float* _dst = &tile[(SLOT)][ldsoff];                                   \
        _Pragma("unroll")                                                      \
        for (int _r = 0; _r < 2; ++_r) {                                       \
            const int _i = tid + _r * 256;                                     \
            if (_i < count4)                                                   \
                __builtin_amdgcn_global_load_lds(                              \
                    (const __attribute__((address_space(1))) unsigned int*)(_src + (size_t)_i * 4), \
                    (__attribute__((address_space(3))) unsigned int*)(_dst + _i * 4), \
                    16, 0, 0);                                                 \
        }                                                                      \
    } while (0)

    // prologue: fill the 3-deep pipe (6 gload_lds per wave outstanding)
    STAGE(0, 0);
    STAGE(1, 1);
    STAGE(2, 2);
    asm volatile("s_waitcnt lgkmcnt(0)" ::: "memory");  // own init ds_writes done

    int slot = 0;
#pragma unroll 1
    for (int ic = 0; ic < CIN; ++ic) {
        // wait for THIS wave's stage of buf `ic` (oldest 2 of outstanding)
        if (ic < CIN - 2)       asm volatile("s_waitcnt vmcnt(4)" ::: "memory");
        else if (ic == CIN - 2) asm volatile("s_waitcnt vmcnt(2)" ::: "memory");
        else                    asm volatile("s_waitcnt vmcnt(0)" ::: "memory");
        __builtin_amdgcn_s_barrier();           // all waves' shares landed
        __builtin_amdgcn_sched_barrier(0);

        const float* tl = tile[slot];
        const float* wap = wlds + ic * 9;          // oc = 0
        const float* wbp = wlds + (CIN + ic) * 9;  // oc = 1
#pragma unroll
        for (int dr = 0; dr < 3; ++dr) {
            const int base = (ty + dr) * HW + col0;
            float v[9];
            v[0] = tl[base + loff] * lmask;
#pragma unroll
            for (int k = 1; k <= 7; ++k) v[k] = tl[base + (k - 1)];
            v[8] = tl[base + roff] * rmask;
            const float a0 = wap[dr * 3 + 0], a1 = wap[dr * 3 + 1], a2 = wap[dr * 3 + 2];
            const float c0 = wbp[dr * 3 + 0], c1 = wbp[dr * 3 + 1], c2 = wbp[dr * 3 + 2];
#pragma unroll
            for (int j = 0; j < 7; ++j) {
                acc0[j] += a0 * v[j] + a1 * v[j + 1] + a2 * v[j + 2];
                acc1[j] += c0 * v[j] + c1 * v[j + 1] + c2 * v[j + 2];
            }
        }

        asm volatile("s_waitcnt lgkmcnt(0)" ::: "memory");  // own reads of slot done
        __builtin_amdgcn_sched_barrier(0);
        __builtin_amdgcn_s_barrier();           // all waves done reading slot
        if (ic + 3 < CIN) STAGE(ic + 3, slot);  // overwrite slot with ch ic+3
        slot = (slot == 2) ? 0 : slot + 1;
    }
#undef STAGE

    float* g0 = g + (size_t)(n * 2 + 0) * HW2 + (size_t)(h0 + ty) * HW + col0;
    float* g1 = g + (size_t)(n * 2 + 1) * HW2 + (size_t)(h0 + ty) * HW + col0;
#pragma unroll
    for (int j = 0; j < 7; ++j) {
        g0[j] = gelu_exact(acc0[j] + bb0);
        g1[j] = gelu_exact(acc1[j] + bb1);
    }
}

// K2: s0 = softmax(gelu(conv3x3(g, w2) + b2))[ch 0]  (softmax2 == sigmoid)
__global__ __launch_bounds__(448) void k2_conv2_softmax(
    const float* __restrict__ g, const float* __restrict__ w2,
    const float* __restrict__ b2, float* __restrict__ s0) {
    const int n  = blockIdx.y;
    const int h  = blockIdx.x * 16 + threadIdx.y;
    const int w0 = threadIdx.x * 4;

    float accA[4], accB[4];
    const float bb0 = b2[0], bb1 = b2[1];
#pragma unroll
    for (int j = 0; j < 4; ++j) { accA[j] = bb0; accB[j] = bb1; }

#pragma unroll
    for (int c = 0; c < 2; ++c) {
        const float* gc = g + (size_t)(n * 2 + c) * HW2;
        const float* wa = w2 + c * 9;
        const float* wb = w2 + (2 + c) * 9;
#pragma unroll
        for (int dh = -1; dh <= 1; ++dh) {
            const int hh = h + dh;
            if (hh < 0 || hh >= HW) continue;
            const float* gr = gc + hh * HW;
            const float4 c4  = *reinterpret_cast<const float4*>(gr + w0);
            const float left  = (w0 > 0)      ? gr[w0 - 1] : 0.0f;
            const float right = (w0 + 4 < HW) ? gr[w0 + 4] : 0.0f;
            const float v0 = left, v1 = c4.x, v2 = c4.y, v3 = c4.z, v4 = c4.w, v5 = right;
            const int r = (dh + 1) * 3;
            const float a0 = wa[r], a1 = wa[r + 1], a2 = wa[r + 2];
            const float c0 = wb[r], c1 = wb[r + 1], c2 = wb[r + 2];
            accA[0] += a0 * v0 + a1 * v1 + a2 * v2;
            accA[1] += a0 * v1 + a1 * v2 + a2 * v3;
            accA[2] += a0 * v2 + a1 * v3 + a2 * v4;
            accA[3] += a0 * v3 + a1 * v4 + a2 * v5;
            accB[0] += c0 * v0 + c1 * v1 + c2 * v2;
            accB[1] += c0 * v1 + c1 * v2 + c2 * v3;
            accB[2] += c0 * v2 + c1 * v3 + c2 * v4;
            accB[3] += c0 * v3 + c1 * v4 + c2 * v5;
        }
    }

    float4 o;
    o.x = 1.0f / (1.0f + expf(gelu_exact(accB[0]) - gelu_exact(accA[0])));
    o.y = 1.0f / (1.0f + expf(gelu_exact(accB[1]) - gelu_exact(accA[1])));
    o.z = 1.0f / (1.0f + expf(gelu_exact(accB[2]) - gelu_exact(accA[2])));
    o.w = 1.0f / (1.0f + expf(gelu_exact(accB[3]) - gelu_exact(accA[3])));
    *reinterpret_cast<float4*>(s0 + (size_t)n * HW2 + h * HW + w0) = o;
}

// K3: out[b][c][t][h][w] = s0*x1 + (1-s0)*x2
__global__ __launch_bounds__(256) void k3_blend(
    const float* __restrict__ x, const float* __restrict__ s0,
    float* __restrict__ out, int total4) {
    int idx = blockIdx.x * blockDim.x + threadIdx.x;
    if (idx >= total4) return;
    const int W4 = HW / 4;
    int w4  = idx % W4;
    int tmp = idx / W4;
    int h   = tmp % HW; tmp /= HW;
    int t   = tmp % 16; tmp /= 16;
    int c   = tmp % 64;
    int b   = tmp / 64;
    const int n = b * 16 + t;

    const size_t px = (size_t)h * HW + w4 * 4;
    const float4 x1 = *reinterpret_cast<const float4*>(x + (size_t)(n * CIN + c)      * HW2 + px);
    const float4 x2 = *reinterpret_cast<const float4*>(x + (size_t)(n * CIN + c + 64) * HW2 + px);
    const float4 s  = *reinterpret_cast<const float4*>(s0 + (size_t)n * HW2 + px);

    float4 o;
    o.x = s.x * x1.x + (1.0f - s.x) * x2.x;
    o.y = s.y * x1.y + (1.0f - s.y) * x2.y;
    o.z = s.z * x1.z + (1.0f - s.z) * x2.z;
    o.w = s.w * x1.w + (1.0f - s.w) * x2.w;
    *reinterpret_cast<float4*>(out + (size_t)idx * 4) = o;
}

extern "C" void kernel_launch(void* const* d_in, const int* in_sizes, int n_in,
                              void* d_out, int out_size, void* d_ws, size_t ws_size,
                              hipStream_t stream) {
    const float* x  = (const float*)d_in[0];
    const float* w1 = (const float*)d_in[1];
    const float* b1 = (const float*)d_in[2];
    const float* w2 = (const float*)d_in[3];
    const float* b2 = (const float*)d_in[4];
    float* out = (float*)d_out;

    const size_t gF  = (size_t)NIMG * 2 * HW2;   // 6.4 MB
    float* g  = (float*)d_ws;
    float* s0 = g + gF;                          // 3.2 MB

    dim3 grd(7, NIMG);
    k1_conv_gelu<<<grd, 256, 0, stream>>>(x, w1, b1, g);

    dim3 blk2(28, 16);
    k2_conv2_softmax<<<grd, blk2, 0, stream>>>(g, w2, b2, s0);

    const int total4 = 4 * 64 * 16 * HW * (HW / 4);
    k3_blend<<<(total4 + 255) / 256, 256, 0, stream>>>(x, s0, out, total4);
}